// Round 11
// baseline (79.637 us; speedup 1.0000x reference)
//
#include <hip/hip_runtime.h>
#include <math.h>

// Linear attention (elu+1 feature map), N=4, L=S=8192, H=8, D=Dv=64, fp32.
//
// out[n,l,h,:] = (qf[n,l,h,:] @ KV[n,h,:,:]) / (qf[n,l,h,:] . ksum[n,h,:] + eps)
// KV[n,h,d,dv] = sum_s kf[n,s,h,d] * vm[n,s,h,dv],  ksum = sum_s kf
//
// Both GEMM phases use split-bf16 MFMA (x = hi + lo; three products hh+lh+hl,
// fp32 accumulate). Dropped ll term ~2^-18 relative. Denominators pure fp32.
// State format (per pair, STATE=4160 words): KVT_hi bf16[64][64] (2048 u32),
// KVT_lo bf16[64][64] (2048 u32), ksum fp32[64].
//
// R11 experiment: k1 reads k and v at IDENTICAL offsets in two same-sized
// buffers -> paired loads hit the same HBM channel (k1 pinned at ~2.2 TB/s in
// every structural variant R4-R10, while k3's single-stream q read runs
// 5.8 TB/s with the same strided pattern). Fix: each thread's v-rows are
// shifted +16 s-rows (32 KB) relative to its k-rows; LDS destination shifts
// correspondingly, so the staged tile (and all math) is unchanged.

#define EPS 1e-6f

static constexpr int Nc = 4;
static constexpr int Lc = 8192;
static constexpr int Sc = 8192;
static constexpr int Hc = 8;
static constexpr int NH = Nc * Hc;         // 32
static constexpr int STATE = 64 * 64 + 64; // 4160 words per (n,h)
static constexpr int TS = 32;              // s-rows per staged tile in k1
static constexpr int TSP = 36;             // k1 bf16 LDS stride
static constexpr int QSP = 68;             // k3 bf16 LDS stride (also fp32 out stride)

typedef __attribute__((ext_vector_type(4))) short short4v;
typedef __attribute__((ext_vector_type(8))) short short8v;
typedef __attribute__((ext_vector_type(4))) float f32x4;

__device__ __forceinline__ float fmap(float x) {
    return x > 0.f ? x + 1.f : __expf(x);
}
__device__ __forceinline__ unsigned short f2bf(float x) {   // RNE float->bf16
    unsigned int u = __float_as_uint(x);
    u += 0x7FFFu + ((u >> 16) & 1u);
    return (unsigned short)(u >> 16);
}
__device__ __forceinline__ float bf2f(unsigned short h) {
    return __uint_as_float(((unsigned int)h) << 16);
}
__device__ __forceinline__ short8v ld8(const unsigned short* p) {
    short4v a = *(const short4v*)p;
    short4v b = *(const short4v*)(p + 4);
    return __builtin_shufflevector(a, b, 0, 1, 2, 3, 4, 5, 6, 7);
}
__device__ __forceinline__ unsigned int pack2(unsigned short a, unsigned short b) {
    return (unsigned)a | ((unsigned)b << 16);
}

struct K1Tile {
    float4 k0, k1, v0, v1;
    float mk0, mk1, mv0, mv1;
};

// ---------------------------------------------------------------------------
// Kernel 1 (MFMA): partial KV + ksum per (pair, chunk).
// grid.x = NH * chunks, block = 256 (4 waves).  sc multiple of 64.
// Thread t stages k rows {2g,2g+1} and v rows {(2g+16)&31, +1} of each tile
// (v shifted 16 rows = 32 KB to decorrelate HBM channels across the two
// streams). Output: fp32 KV[d][dv] + ksum at 4096 (reduced by k2/k2b).
// ---------------------------------------------------------------------------
__global__ __launch_bounds__(256, 4) void k1_partial(
    const float* __restrict__ kg, const float* __restrict__ vg,
    const float* __restrict__ kv_mask,
    float* __restrict__ partial, int chunks, int sc)
{
    __shared__ unsigned short kTh[64][TSP], kTl[64][TSP];
    __shared__ unsigned short vTh[64][TSP], vTl[64][TSP];
    __shared__ float ksb[16][64];

    const int bid = blockIdx.x;
    const int pair = bid / chunks;
    const int chunk = bid - pair * chunks;
    const int n = pair >> 3;
    const int h = pair & 7;
    const int s0 = chunk * sc;
    const int t = threadIdx.x;
    const int g = t >> 4;            // 0..15 (s-pair group)
    const int c4 = (t & 15) * 4;     // d/dv column base
    const int lane = t & 63;
    const int wv = t >> 6;           // wave id 0..3
    const int row16 = lane & 15;
    const int g8 = (lane >> 4) * 8;  // k-slice base within 32

    const int rk = 2 * g;                 // k rows within tile
    const int rv = (2 * g + 16) & 31;     // v rows within tile (shifted)

    f32x4 acc[4] = {{0.f,0.f,0.f,0.f},{0.f,0.f,0.f,0.f},
                    {0.f,0.f,0.f,0.f},{0.f,0.f,0.f,0.f}};
    float ksm[4] = {0.f, 0.f, 0.f, 0.f};

    const size_t rowstride = (size_t)Hc * 64;                      // 512 floats per s
    const size_t gbase = ((size_t)n * Sc * Hc + h) * 64 + c4;
    const int mbase = n * Sc;

    // ---- issue: global loads for one tile into a named register set
    auto issue = [&](int sbase, K1Tile& T) {
        const int sk = s0 + sbase + rk;
        const int sv = s0 + sbase + rv;
        const size_t bek = gbase + (size_t)sk * rowstride;
        const size_t bev = gbase + (size_t)sv * rowstride;
        T.k0 = *(const float4*)(kg + bek);
        T.k1 = *(const float4*)(kg + bek + rowstride);
        T.v0 = *(const float4*)(vg + bev);
        T.v1 = *(const float4*)(vg + bev + rowstride);
        T.mk0 = kv_mask[mbase + sk];
        T.mk1 = kv_mask[mbase + sk + 1];
        T.mv0 = kv_mask[mbase + sv];
        T.mv1 = kv_mask[mbase + sv + 1];
    };

    // ---- process: convert+stage one tile, then MFMA it
    auto process = [&](const K1Tile& T) {
        const float* kep = &T.k0.x;
        const float* kop = &T.k1.x;
        const float* vep = &T.v0.x;
        const float* vop = &T.v1.x;
        #pragma unroll
        for (int j = 0; j < 4; ++j) {
            const float fe = T.mk0 * fmap(kep[j]);
            const float fo = T.mk1 * fmap(kop[j]);
            ksm[j] += fe + fo;
            const unsigned short he = f2bf(fe), ho = f2bf(fo);
            const unsigned short le = f2bf(fe - bf2f(he)), lo_ = f2bf(fo - bf2f(ho));
            *(unsigned int*)&kTh[c4 + j][rk] = pack2(he, ho);
            *(unsigned int*)&kTl[c4 + j][rk] = pack2(le, lo_);
            const float ue = T.mv0 * vep[j];
            const float uo = T.mv1 * vop[j];
            const unsigned short vhe = f2bf(ue), vho = f2bf(uo);
            const unsigned short vle = f2bf(ue - bf2f(vhe)), vlo = f2bf(uo - bf2f(vho));
            *(unsigned int*)&vTh[c4 + j][rv] = pack2(vhe, vho);
            *(unsigned int*)&vTl[c4 + j][rv] = pack2(vle, vlo);
        }
        __syncthreads();

        const short8v Ah = ld8(&kTh[wv * 16 + row16][g8]);
        const short8v Al = ld8(&kTl[wv * 16 + row16][g8]);
        #pragma unroll
        for (int bt = 0; bt < 4; ++bt) {
            const short8v Bh = ld8(&vTh[bt * 16 + row16][g8]);
            const short8v Bl = ld8(&vTl[bt * 16 + row16][g8]);
            acc[bt] = __builtin_amdgcn_mfma_f32_16x16x32_bf16(Ah, Bh, acc[bt], 0, 0, 0);
            acc[bt] = __builtin_amdgcn_mfma_f32_16x16x32_bf16(Al, Bh, acc[bt], 0, 0, 0);
            acc[bt] = __builtin_amdgcn_mfma_f32_16x16x32_bf16(Ah, Bl, acc[bt], 0, 0, 0);
        }
        __syncthreads();
    };

    // ---- ping-pong software pipeline, 2 tiles per loop trip
    K1Tile A, B;
    issue(0, A);
    for (int sb = 0; sb < sc; sb += 2 * TS) {
        issue(sb + TS, B);
        process(A);
        const int na = (sb + 2 * TS < sc) ? sb + 2 * TS : sb;   // clamp at tail
        issue(na, A);
        process(B);
    }

    // ---- epilogue: stage partial KV through LDS, store coalesced float4
    float* outp = partial + (size_t)bid * STATE;
    float (*outs)[QSP] = reinterpret_cast<float (*)[QSP]>(&kTh[0][0]);
    #pragma unroll
    for (int bt = 0; bt < 4; ++bt) {
        #pragma unroll
        for (int r = 0; r < 4; ++r) {
            const int row = wv * 16 + (lane >> 4) * 4 + r;   // D: col=lane&15
            outs[row][bt * 16 + row16] = acc[bt][r];
        }
    }
    __syncthreads();
    #pragma unroll
    for (int p = 0; p < 4; ++p) {
        const int f = t + p * 256;          // float4 index over [64][16]
        const int row = f >> 4;
        const int cc = (f & 15) * 4;
        *(float4*)(outp + row * 64 + cc) = *(const float4*)&outs[row][cc];
    }

    // ---- ksum reduce (exact fp32)
    *(f32x4*)&ksb[g][c4] = (f32x4){ksm[0], ksm[1], ksm[2], ksm[3]};
    __syncthreads();
    if (t < 64) {
        float s = 0.f;
        #pragma unroll
        for (int i = 0; i < 16; ++i) s += ksb[i][t];
        outp[4096 + t] = s;
    }
}

// ---------------------------------------------------------------------------
// Kernel 2: fp32 reduce of nred consecutive STATE blocks -> 1, per group.
// ---------------------------------------------------------------------------
__global__ __launch_bounds__(256) void k2_reduce(
    const float* __restrict__ src, float* __restrict__ dst, int nred)
{
    const int p = blockIdx.x / 5;
    const int seg = blockIdx.x - p * 5;
    const int e4 = seg * 256 + threadIdx.x;
    if (e4 >= STATE / 4) return;
    const float4* s = (const float4*)(src + (size_t)p * nred * STATE) + e4;
    float4 acc = make_float4(0.f, 0.f, 0.f, 0.f);
    #pragma unroll 4
    for (int j = 0; j < nred; ++j) {
        float4 x = s[(size_t)j * (STATE / 4)];
        acc.x += x.x; acc.y += x.y; acc.z += x.z; acc.w += x.w;
    }
    ((float4*)(dst + (size_t)p * STATE))[e4] = acc;
}

// ---------------------------------------------------------------------------
// Kernel 2b: final reduce + convert to k3 state format.
// grid = NH blocks; reduces nred old-format partials, emits
// KVT_hi bf16[dv][d], KVT_lo bf16[dv][d], ksum fp32[64].
// ---------------------------------------------------------------------------
__global__ __launch_bounds__(256) void k2b_finalize(
    const float* __restrict__ src, float* __restrict__ dst, int nred)
{
    __shared__ float kv[64][QSP];   // fp32 KV[d][dv], padded
    __shared__ float kss[64];

    const int pair = blockIdx.x;
    const int t = threadIdx.x;
    const float4* sbase = (const float4*)(src + (size_t)pair * nred * STATE);

    #pragma unroll
    for (int i = 0; i < 4; ++i) {
        const int e4 = t + i * 256;            // 0..1023 (float4 idx over KV)
        float4 a = make_float4(0.f, 0.f, 0.f, 0.f);
        for (int j = 0; j < nred; ++j) {
            float4 x = sbase[(size_t)j * (STATE / 4) + e4];
            a.x += x.x; a.y += x.y; a.z += x.z; a.w += x.w;
        }
        *(float4*)&kv[e4 >> 4][(e4 & 15) * 4] = a;
    }
    if (t < 16) {
        float4 a = make_float4(0.f, 0.f, 0.f, 0.f);
        for (int j = 0; j < nred; ++j) {
            float4 x = sbase[(size_t)j * (STATE / 4) + 1024 + t];
            a.x += x.x; a.y += x.y; a.z += x.z; a.w += x.w;
        }
        *(float4*)&kss[t * 4] = a;
    }
    __syncthreads();

    unsigned int* dw = (unsigned int*)(dst + (size_t)pair * STATE);
    #pragma unroll
    for (int i = 0; i < 8; ++i) {
        const int w = t + i * 256;             // 0..2047
        const int dv = w >> 5;
        const int d0 = (w & 31) * 2;
        const float f0 = kv[d0][dv];
        const float f1 = kv[d0 + 1][dv];
        const unsigned short h0 = f2bf(f0), h1 = f2bf(f1);
        dw[w] = pack2(h0, h1);
        dw[2048 + w] = pack2(f2bf(f0 - bf2f(h0)), f2bf(f1 - bf2f(h1)));
    }
    if (t < 64) dst[(size_t)pair * STATE + 4096 + t] = kss[t];
}

// ---------------------------------------------------------------------------
// Kernel 3 (MFMA): out tile 64 l-rows x 64 dv per block for one (n,h).
// grid.x = NH * (L/64), block = 256 (4 waves; wave wv owns l-band 16wv..16wv+15).
// ---------------------------------------------------------------------------
__global__ __launch_bounds__(256, 4) void k3_out(
    const float* __restrict__ qg, const float* __restrict__ state,
    const float* __restrict__ q_mask, float* __restrict__ outg)
{
    __shared__ __align__(16) unsigned short qsp[2][64][QSP]; // q hi/lo; reused as fp32 out
    __shared__ unsigned short kvt[2][64][QSP];               // KVT hi/lo [dv][d]
    __shared__ float ksum[64];
    __shared__ float dinv[64];

    const int nblk = Lc / 64;           // 128
    const int bid = blockIdx.x;
    const int pair = bid / nblk;
    const int lblk = bid - pair * nblk;
    const int n = pair >> 3;
    const int h = pair & 7;
    const int l0 = lblk * 64;
    const int t = threadIdx.x;
    const int lane = t & 63;
    const int wv = t >> 6;
    const int row16 = lane & 15;
    const int g8 = (lane >> 4) * 8;

    // ---- stage state: KVT hi/lo into padded LDS + ksum
    const unsigned int* sw = (const unsigned int*)(state + (size_t)pair * STATE);
    #pragma unroll
    for (int i = 0; i < 8; ++i) {
        const int w = t + i * 256;          // 0..2047
        const int dv = w >> 5;
        const int d2 = (w & 31) * 2;
        *(unsigned int*)&kvt[0][dv][d2] = sw[w];
        *(unsigned int*)&kvt[1][dv][d2] = sw[2048 + w];
    }
    if (t < 64) ksum[t] = ((const float*)state)[(size_t)pair * STATE + 4096 + t];
    __syncthreads();

    // ---- stage q (fmap+mask, split bf16) + denominators (fp32)
    #pragma unroll
    for (int p = 0; p < 4; ++p) {
        const int f = t + p * 256;
        const int row = f >> 4;
        const int c4 = (f & 15) * 4;
        const int l = l0 + row;
        const size_t base = ((size_t)(n * Lc + l) * Hc + h) * 64 + c4;
        const float4 qq = *(const float4*)(qg + base);
        const float m = q_mask[n * Lc + l];
        const float q0 = m * fmap(qq.x), q1 = m * fmap(qq.y);
        const float q2 = m * fmap(qq.z), q3 = m * fmap(qq.w);
        const unsigned short h0 = f2bf(q0), h1 = f2bf(q1), h2 = f2bf(q2), h3 = f2bf(q3);
        *(unsigned int*)&qsp[0][row][c4]     = pack2(h0, h1);
        *(unsigned int*)&qsp[0][row][c4 + 2] = pack2(h2, h3);
        *(unsigned int*)&qsp[1][row][c4]     = pack2(f2bf(q0 - bf2f(h0)), f2bf(q1 - bf2f(h1)));
        *(unsigned int*)&qsp[1][row][c4 + 2] = pack2(f2bf(q2 - bf2f(h2)), f2bf(q3 - bf2f(h3)));
        float dp = q0 * ksum[c4] + q1 * ksum[c4 + 1] + q2 * ksum[c4 + 2] + q3 * ksum[c4 + 3];
        dp += __shfl_xor(dp, 1);
        dp += __shfl_xor(dp, 2);
        dp += __shfl_xor(dp, 4);
        dp += __shfl_xor(dp, 8);
        if ((t & 15) == 0) dinv[row] = 1.0f / (dp + EPS);
    }
    __syncthreads();

    // ---- MFMA: out[l][dv] = sum_d qf[l][d] * KVT[dv][d]
    f32x4 acc[4] = {{0.f,0.f,0.f,0.f},{0.f,0.f,0.f,0.f},
                    {0.f,0.f,0.f,0.f},{0.f,0.f,0.f,0.f}};
    #pragma unroll
    for (int ks = 0; ks < 2; ++ks) {
        const short8v Ah = ld8(&qsp[0][wv * 16 + row16][ks * 32 + g8]);
        const short8v Al = ld8(&qsp[1][wv * 16 + row16][ks * 32 + g8]);
        #pragma unroll
        for (int bt = 0; bt < 4; ++bt) {
            const short8v Bh = ld8(&kvt[0][bt * 16 + row16][ks * 32 + g8]);
            const short8v Bl = ld8(&kvt[1][bt * 16 + row16][ks * 32 + g8]);
            acc[bt] = __builtin_amdgcn_mfma_f32_16x16x32_bf16(Ah, Bh, acc[bt], 0, 0, 0);
            acc[bt] = __builtin_amdgcn_mfma_f32_16x16x32_bf16(Al, Bh, acc[bt], 0, 0, 0);
            acc[bt] = __builtin_amdgcn_mfma_f32_16x16x32_bf16(Ah, Bl, acc[bt], 0, 0, 0);
        }
    }
    __syncthreads();   // all A/B reads done; qsp may be reused

    // ---- scale + transpose through LDS (reuse qsp as fp32 [64][QSP])
    float (*outs)[QSP] = reinterpret_cast<float (*)[QSP]>(&qsp[0][0][0]);
    #pragma unroll
    for (int bt = 0; bt < 4; ++bt) {
        #pragma unroll
        for (int r = 0; r < 4; ++r) {
            const int row = wv * 16 + (lane >> 4) * 4 + r;
            outs[row][bt * 16 + row16] = acc[bt][r] * dinv[row];
        }
    }
    __syncthreads();

    // ---- coalesced float4 store
    #pragma unroll
    for (int p = 0; p < 4; ++p) {
        const int f = t + p * 256;
        const int row = f >> 4;
        const int c4 = (f & 15) * 4;
        const size_t base = ((size_t)(n * Lc + l0 + row) * Hc + h) * 64 + c4;
        *(float4*)(outg + base) = *(const float4*)&outs[row][c4];
    }
}

// ---------------------------------------------------------------------------
extern "C" void kernel_launch(void* const* d_in, const int* in_sizes, int n_in,
                              void* d_out, int out_size, void* d_ws, size_t ws_size,
                              hipStream_t stream)
{
    (void)in_sizes; (void)n_in; (void)out_size;
    const float* q       = (const float*)d_in[0];
    const float* k       = (const float*)d_in[1];
    const float* v       = (const float*)d_in[2];
    const float* q_mask  = (const float*)d_in[3];
    const float* kv_mask = (const float*)d_in[4];
    float* out = (float*)d_out;

    const size_t stBytes  = (size_t)STATE * sizeof(float);      // 16640
    const size_t finBytes = (size_t)NH * stBytes;               // 532480
    const size_t p2Bytes  = (size_t)NH * 4 * stBytes;           // ~2.1 MB

    float* fin = (float*)d_ws;
    float* p2  = (float*)((char*)d_ws + finBytes);
    float* p1  = (float*)((char*)d_ws + finBytes + p2Bytes);

    int chunks = 0;
    for (int c = 32; c >= 8; c >>= 1) {
        if (ws_size >= finBytes + p2Bytes + (size_t)NH * c * stBytes) { chunks = c; break; }
    }

    if (chunks >= 8) {
        k1_partial<<<NH * chunks, 256, 0, stream>>>(k, v, kv_mask, p1, chunks, Sc / chunks);
        k2_reduce<<<NH * 4 * 5, 256, 0, stream>>>(p1, p2, chunks / 4);       // chunks -> 4
        k2b_finalize<<<NH, 256, 0, stream>>>(p2, fin, 4);                    // 4 -> state
    } else {
        // small-workspace fallback: single chunk, then convert
        float* p1fb = (float*)((char*)d_ws + finBytes);
        k1_partial<<<NH, 256, 0, stream>>>(k, v, kv_mask, p1fb, 1, Sc);
        k2b_finalize<<<NH, 256, 0, stream>>>(p1fb, fin, 1);
    }

    k3_out<<<NH * (Lc / 64), 256, 0, stream>>>(q, fin, q_mask, out);
}

// Round 12
// 74.699 us; speedup vs baseline: 1.0661x; 1.0661x over previous
//
#include <hip/hip_runtime.h>
#include <math.h>

// Linear attention (elu+1 feature map), N=4, L=S=8192, H=8, D=Dv=64, fp32.
//
// out[n,l,h,:] = (qf[n,l,h,:] @ KV[n,h,:,:]) / (qf[n,l,h,:] . ksum[n,h,:] + eps)
// KV[n,h,d,dv] = sum_s kf[n,s,h,d] * vm[n,s,h,dv],  ksum = sum_s kf
//
// Both GEMM phases use split-bf16 MFMA (x = hi + lo; three products hh+lh+hl,
// fp32 accumulate). Dropped ll term ~2^-18 relative. Denominators pure fp32.
// State format (per pair, STATE=4160 words): KVT_hi bf16[64][64] (2048 u32),
// KVT_lo bf16[64][64] (2048 u32), ksum fp32[64].
//
// R12 structure: 3 launches (was 4).
//  k1  (R10 verbatim): partial KV per (pair, chunk=32), MFMA split-bf16.
//  k2c (new): reduce 32 partials AND emit transposed split-bf16 state in one
//      kernel (each thread reduces d-row pairs so it packs u32 hi/lo itself).
//  k3  (2 l-tiles/block): state staged once per block, grid 4096->2048.

#define EPS 1e-6f

static constexpr int Nc = 4;
static constexpr int Lc = 8192;
static constexpr int Sc = 8192;
static constexpr int Hc = 8;
static constexpr int NH = Nc * Hc;         // 32
static constexpr int STATE = 64 * 64 + 64; // 4160 words per (n,h)
static constexpr int TS = 32;              // s-rows per staged tile in k1
static constexpr int TSP = 36;             // k1 bf16 LDS stride
static constexpr int QSP = 68;             // k3 bf16 LDS stride (also fp32 out stride)

typedef __attribute__((ext_vector_type(4))) short short4v;
typedef __attribute__((ext_vector_type(8))) short short8v;
typedef __attribute__((ext_vector_type(4))) float f32x4;

__device__ __forceinline__ float fmap(float x) {
    return x > 0.f ? x + 1.f : __expf(x);
}
__device__ __forceinline__ unsigned short f2bf(float x) {   // RNE float->bf16
    unsigned int u = __float_as_uint(x);
    u += 0x7FFFu + ((u >> 16) & 1u);
    return (unsigned short)(u >> 16);
}
__device__ __forceinline__ float bf2f(unsigned short h) {
    return __uint_as_float(((unsigned int)h) << 16);
}
__device__ __forceinline__ short8v ld8(const unsigned short* p) {
    short4v a = *(const short4v*)p;
    short4v b = *(const short4v*)(p + 4);
    return __builtin_shufflevector(a, b, 0, 1, 2, 3, 4, 5, 6, 7);
}
__device__ __forceinline__ unsigned int pack2(unsigned short a, unsigned short b) {
    return (unsigned)a | ((unsigned)b << 16);
}

// ---------------------------------------------------------------------------
// Kernel 1 (MFMA): partial KV + ksum per (pair, chunk).  R10 verbatim.
// grid.x = NH * chunks, block = 256 (4 waves).  sc multiple of 64.
// Output layout: fp32 KV[d][dv] + ksum at 4096 (reduced by k2c).
// ---------------------------------------------------------------------------
__global__ __launch_bounds__(256, 4) void k1_partial(
    const float* __restrict__ kg, const float* __restrict__ vg,
    const float* __restrict__ kv_mask,
    float* __restrict__ partial, int chunks, int sc)
{
    __shared__ unsigned short kTh[64][TSP], kTl[64][TSP];
    __shared__ unsigned short vTh[64][TSP], vTl[64][TSP];
    __shared__ float ksb[16][64];

    const int bid = blockIdx.x;
    const int pair = bid / chunks;
    const int chunk = bid - pair * chunks;
    const int n = pair >> 3;
    const int h = pair & 7;
    const int s0 = chunk * sc;
    const int t = threadIdx.x;
    const int g = t >> 4;            // 0..15 (s-pair group)
    const int c4 = (t & 15) * 4;     // d/dv column base
    const int lane = t & 63;
    const int wv = t >> 6;           // wave id 0..3
    const int row16 = lane & 15;
    const int g8 = (lane >> 4) * 8;  // k-slice base within 32

    f32x4 acc[4] = {{0.f,0.f,0.f,0.f},{0.f,0.f,0.f,0.f},
                    {0.f,0.f,0.f,0.f},{0.f,0.f,0.f,0.f}};
    float ksm[4] = {0.f, 0.f, 0.f, 0.f};

    const size_t rowstride = (size_t)Hc * 64;                      // 512 floats per s
    const size_t gbase = ((size_t)n * Sc * Hc + h) * 64 + c4;
    const int mbase = n * Sc;

    auto issue = [&](int sbase, float4& a0, float4& a1, float4& b0, float4& b1,
                     float& me, float& mo) {
        const int s = s0 + sbase + 2 * g;
        const size_t be = gbase + (size_t)s * rowstride;
        a0 = *(const float4*)(kg + be);
        a1 = *(const float4*)(kg + be + rowstride);
        b0 = *(const float4*)(vg + be);
        b1 = *(const float4*)(vg + be + rowstride);
        me = kv_mask[mbase + s];
        mo = kv_mask[mbase + s + 1];
    };

    auto process = [&](const float4& ck0, const float4& ck1,
                       const float4& cv0, const float4& cv1,
                       float cme, float cmo) {
        const float* kep = &ck0.x;
        const float* kop = &ck1.x;
        const float* vep = &cv0.x;
        const float* vop = &cv1.x;
        #pragma unroll
        for (int j = 0; j < 4; ++j) {
            const float fe = cme * fmap(kep[j]);
            const float fo = cmo * fmap(kop[j]);
            ksm[j] += fe + fo;
            const unsigned short he = f2bf(fe), ho = f2bf(fo);
            const unsigned short le = f2bf(fe - bf2f(he)), lo_ = f2bf(fo - bf2f(ho));
            *(unsigned int*)&kTh[c4 + j][2 * g] = pack2(he, ho);
            *(unsigned int*)&kTl[c4 + j][2 * g] = pack2(le, lo_);
            const float ue = cme * vep[j];
            const float uo = cmo * vop[j];
            const unsigned short vhe = f2bf(ue), vho = f2bf(uo);
            const unsigned short vle = f2bf(ue - bf2f(vhe)), vlo = f2bf(uo - bf2f(vho));
            *(unsigned int*)&vTh[c4 + j][2 * g] = pack2(vhe, vho);
            *(unsigned int*)&vTl[c4 + j][2 * g] = pack2(vle, vlo);
        }
        __syncthreads();

        const short8v Ah = ld8(&kTh[wv * 16 + row16][g8]);
        const short8v Al = ld8(&kTl[wv * 16 + row16][g8]);
        #pragma unroll
        for (int bt = 0; bt < 4; ++bt) {
            const short8v Bh = ld8(&vTh[bt * 16 + row16][g8]);
            const short8v Bl = ld8(&vTl[bt * 16 + row16][g8]);
            acc[bt] = __builtin_amdgcn_mfma_f32_16x16x32_bf16(Ah, Bh, acc[bt], 0, 0, 0);
            acc[bt] = __builtin_amdgcn_mfma_f32_16x16x32_bf16(Al, Bh, acc[bt], 0, 0, 0);
            acc[bt] = __builtin_amdgcn_mfma_f32_16x16x32_bf16(Ah, Bl, acc[bt], 0, 0, 0);
        }
        __syncthreads();
    };

    float4 ka0, ka1, va0, va1, kb0, kb1, vb0, vb1;
    float mea, moa, meb, mob;

    issue(0, ka0, ka1, va0, va1, mea, moa);
    for (int sb = 0; sb < sc; sb += 2 * TS) {
        issue(sb + TS, kb0, kb1, vb0, vb1, meb, mob);
        process(ka0, ka1, va0, va1, mea, moa);
        const int na = (sb + 2 * TS < sc) ? sb + 2 * TS : sb;   // clamp at tail
        issue(na, ka0, ka1, va0, va1, mea, moa);
        process(kb0, kb1, vb0, vb1, meb, mob);
    }

    // ---- epilogue: stage partial KV through LDS, store coalesced float4
    float* outp = partial + (size_t)bid * STATE;
    float (*outs)[QSP] = reinterpret_cast<float (*)[QSP]>(&kTh[0][0]);
    #pragma unroll
    for (int bt = 0; bt < 4; ++bt) {
        #pragma unroll
        for (int r = 0; r < 4; ++r) {
            const int row = wv * 16 + (lane >> 4) * 4 + r;   // D: col=lane&15
            outs[row][bt * 16 + row16] = acc[bt][r];
        }
    }
    __syncthreads();
    #pragma unroll
    for (int p = 0; p < 4; ++p) {
        const int f = t + p * 256;          // float4 index over [64][16]
        const int row = f >> 4;
        const int cc = (f & 15) * 4;
        *(float4*)(outp + row * 64 + cc) = *(const float4*)&outs[row][cc];
    }

    // ---- ksum reduce (exact fp32)
    *(f32x4*)&ksb[g][c4] = (f32x4){ksm[0], ksm[1], ksm[2], ksm[3]};
    __syncthreads();
    if (t < 64) {
        float s = 0.f;
        #pragma unroll
        for (int i = 0; i < 16; ++i) s += ksb[i][t];
        outp[4096 + t] = s;
    }
}

// ---------------------------------------------------------------------------
// Kernel 2c: fused reduce + finalize.  grid = NH * 2 blocks of 256.
// Thread (sub*256+t) = ep in [0,512) owns KV rows d0=(ep>>4)*2, d0+1, cols
// c4..c4+3: reduces nred partials in fp32, then packs transposed split-bf16
// state words directly (w = dv*32 + d0/2, hi at w, lo at 2048+w).
// ksum reduced by threads t<16 of sub==0.
// ---------------------------------------------------------------------------
__global__ __launch_bounds__(256) void k2c_reduce_finalize(
    const float* __restrict__ src, float* __restrict__ dst, int nred)
{
    const int b = blockIdx.x;
    const int pair = b >> 1;
    const int sub = b & 1;
    const int t = threadIdx.x;
    const int ep = sub * 256 + t;          // 0..511
    const int d0 = (ep >> 4) * 2;          // 0,2,..,62
    const int c4 = (ep & 15) * 4;

    const float* sbase = src + (size_t)pair * nred * STATE;
    f32x4 a0 = {0.f,0.f,0.f,0.f}, a1 = {0.f,0.f,0.f,0.f};
    #pragma unroll 4
    for (int j = 0; j < nred; ++j) {
        const float* pj = sbase + (size_t)j * STATE;
        a0 += *(const f32x4*)(pj + (size_t)d0 * 64 + c4);
        a1 += *(const f32x4*)(pj + (size_t)(d0 + 1) * 64 + c4);
    }

    unsigned int* dw = (unsigned int*)(dst + (size_t)pair * STATE);
    #pragma unroll
    for (int i = 0; i < 4; ++i) {
        const int w = (c4 + i) * 32 + (d0 >> 1);
        const unsigned short h0 = f2bf(a0[i]), h1 = f2bf(a1[i]);
        dw[w] = pack2(h0, h1);
        dw[2048 + w] = pack2(f2bf(a0[i] - bf2f(h0)), f2bf(a1[i] - bf2f(h1)));
    }

    if (sub == 0 && t < 16) {
        f32x4 a = {0.f,0.f,0.f,0.f};
        #pragma unroll 4
        for (int j = 0; j < nred; ++j)
            a += *(const f32x4*)(sbase + (size_t)j * STATE + 4096 + t * 4);
        *(f32x4*)(dst + (size_t)pair * STATE + 4096 + t * 4) = a;
    }
}

// ---------------------------------------------------------------------------
// Kernel 3 (MFMA): TWO 64x64 out tiles per block for one (n,h).
// grid.x = NH * 64, block = 256 (4 waves).  State staged once per block.
// ---------------------------------------------------------------------------
__global__ __launch_bounds__(256, 4) void k3_out(
    const float* __restrict__ qg, const float* __restrict__ state,
    const float* __restrict__ q_mask, float* __restrict__ outg)
{
    __shared__ __align__(16) unsigned short qsp[2][64][QSP]; // q hi/lo; reused as fp32 out
    __shared__ unsigned short kvt[2][64][QSP];               // KVT hi/lo [dv][d]
    __shared__ float ksum[64];
    __shared__ float dinv[64];

    const int nblk = 64;                // tile-pairs per pair
    const int bid = blockIdx.x;
    const int pair = bid / nblk;
    const int lb = (bid - pair * nblk) * 2;   // first of 2 l-tiles
    const int n = pair >> 3;
    const int h = pair & 7;
    const int t = threadIdx.x;
    const int lane = t & 63;
    const int wv = t >> 6;
    const int row16 = lane & 15;
    const int g8 = (lane >> 4) * 8;

    // ---- stage state once: KVT hi/lo into padded LDS + ksum
    const unsigned int* sw = (const unsigned int*)(state + (size_t)pair * STATE);
    #pragma unroll
    for (int i = 0; i < 8; ++i) {
        const int w = t + i * 256;          // 0..2047
        const int dv = w >> 5;
        const int d2 = (w & 31) * 2;
        *(unsigned int*)&kvt[0][dv][d2] = sw[w];
        *(unsigned int*)&kvt[1][dv][d2] = sw[2048 + w];
    }
    if (t < 64) ksum[t] = ((const float*)state)[(size_t)pair * STATE + 4096 + t];
    __syncthreads();

    for (int tl = 0; tl < 2; ++tl) {
        const int l0 = (lb + tl) * 64;

        // ---- stage q (fmap+mask, split bf16) + denominators (fp32)
        #pragma unroll
        for (int p = 0; p < 4; ++p) {
            const int f = t + p * 256;
            const int row = f >> 4;
            const int c4 = (f & 15) * 4;
            const int l = l0 + row;
            const size_t base = ((size_t)(n * Lc + l) * Hc + h) * 64 + c4;
            const float4 qq = *(const float4*)(qg + base);
            const float m = q_mask[n * Lc + l];
            const float q0 = m * fmap(qq.x), q1 = m * fmap(qq.y);
            const float q2 = m * fmap(qq.z), q3 = m * fmap(qq.w);
            const unsigned short h0 = f2bf(q0), h1 = f2bf(q1), h2 = f2bf(q2), h3 = f2bf(q3);
            *(unsigned int*)&qsp[0][row][c4]     = pack2(h0, h1);
            *(unsigned int*)&qsp[0][row][c4 + 2] = pack2(h2, h3);
            *(unsigned int*)&qsp[1][row][c4]     = pack2(f2bf(q0 - bf2f(h0)), f2bf(q1 - bf2f(h1)));
            *(unsigned int*)&qsp[1][row][c4 + 2] = pack2(f2bf(q2 - bf2f(h2)), f2bf(q3 - bf2f(h3)));
            float dp = q0 * ksum[c4] + q1 * ksum[c4 + 1] + q2 * ksum[c4 + 2] + q3 * ksum[c4 + 3];
            dp += __shfl_xor(dp, 1);
            dp += __shfl_xor(dp, 2);
            dp += __shfl_xor(dp, 4);
            dp += __shfl_xor(dp, 8);
            if ((t & 15) == 0) dinv[row] = 1.0f / (dp + EPS);
        }
        __syncthreads();

        // ---- MFMA: out[l][dv] = sum_d qf[l][d] * KVT[dv][d]
        f32x4 acc[4] = {{0.f,0.f,0.f,0.f},{0.f,0.f,0.f,0.f},
                        {0.f,0.f,0.f,0.f},{0.f,0.f,0.f,0.f}};
        #pragma unroll
        for (int ks = 0; ks < 2; ++ks) {
            const short8v Ah = ld8(&qsp[0][wv * 16 + row16][ks * 32 + g8]);
            const short8v Al = ld8(&qsp[1][wv * 16 + row16][ks * 32 + g8]);
            #pragma unroll
            for (int bt = 0; bt < 4; ++bt) {
                const short8v Bh = ld8(&kvt[0][bt * 16 + row16][ks * 32 + g8]);
                const short8v Bl = ld8(&kvt[1][bt * 16 + row16][ks * 32 + g8]);
                acc[bt] = __builtin_amdgcn_mfma_f32_16x16x32_bf16(Ah, Bh, acc[bt], 0, 0, 0);
                acc[bt] = __builtin_amdgcn_mfma_f32_16x16x32_bf16(Al, Bh, acc[bt], 0, 0, 0);
                acc[bt] = __builtin_amdgcn_mfma_f32_16x16x32_bf16(Ah, Bl, acc[bt], 0, 0, 0);
            }
        }
        __syncthreads();   // all A/B reads done; qsp may be reused

        // ---- scale + transpose through LDS (reuse qsp as fp32 [64][QSP])
        float (*outs)[QSP] = reinterpret_cast<float (*)[QSP]>(&qsp[0][0][0]);
        #pragma unroll
        for (int bt = 0; bt < 4; ++bt) {
            #pragma unroll
            for (int r = 0; r < 4; ++r) {
                const int row = wv * 16 + (lane >> 4) * 4 + r;
                outs[row][bt * 16 + row16] = acc[bt][r] * dinv[row];
            }
        }
        __syncthreads();

        // ---- coalesced float4 store
        #pragma unroll
        for (int p = 0; p < 4; ++p) {
            const int f = t + p * 256;
            const int row = f >> 4;
            const int c4 = (f & 15) * 4;
            const size_t base = ((size_t)(n * Lc + l0 + row) * Hc + h) * 64 + c4;
            *(float4*)(outg + base) = *(const float4*)&outs[row][c4];
        }
        __syncthreads();   // outs/dinv dead before next tile overwrites qsp
    }
}

// ---------------------------------------------------------------------------
extern "C" void kernel_launch(void* const* d_in, const int* in_sizes, int n_in,
                              void* d_out, int out_size, void* d_ws, size_t ws_size,
                              hipStream_t stream)
{
    (void)in_sizes; (void)n_in; (void)out_size;
    const float* q       = (const float*)d_in[0];
    const float* k       = (const float*)d_in[1];
    const float* v       = (const float*)d_in[2];
    const float* q_mask  = (const float*)d_in[3];
    const float* kv_mask = (const float*)d_in[4];
    float* out = (float*)d_out;

    const size_t stBytes  = (size_t)STATE * sizeof(float);      // 16640
    const size_t finBytes = (size_t)NH * stBytes;               // 532480

    float* fin = (float*)d_ws;
    float* p1  = (float*)((char*)d_ws + finBytes);

    int chunks = 0;
    for (int c = 32; c >= 8; c >>= 1) {
        if (ws_size >= finBytes + (size_t)NH * c * stBytes) { chunks = c; break; }
    }

    if (chunks >= 8) {
        k1_partial<<<NH * chunks, 256, 0, stream>>>(k, v, kv_mask, p1, chunks, Sc / chunks);
        k2c_reduce_finalize<<<NH * 2, 256, 0, stream>>>(p1, fin, chunks);
    } else {
        // tiny-workspace fallback: single chunk, then convert
        k1_partial<<<NH, 256, 0, stream>>>(k, v, kv_mask, p1, 1, Sc);
        k2c_reduce_finalize<<<NH * 2, 256, 0, stream>>>(p1, fin, 1);
    }

    k3_out<<<NH * 64, 256, 0, stream>>>(q, fin, q_mask, out);
}